// Round 10
// baseline (243.218 us; speedup 1.0000x reference)
//
#include <hip/hip_runtime.h>
#include <hip/hip_bf16.h>
#include <stdint.h>

typedef unsigned short u16;
typedef __attribute__((ext_vector_type(8))) short short8;
typedef __attribute__((ext_vector_type(4))) short s4v;
typedef __attribute__((ext_vector_type(4))) float f32x4;

__device__ __forceinline__ float bf2f(u16 u) {
    union { uint32_t u; float f; } v; v.u = ((uint32_t)u) << 16; return v.f;
}
__device__ __forceinline__ u16 f2bf(float f) {
    union { float f; uint32_t u; } v; v.f = f;
    uint32_t r = (v.u + 0x7fffu + ((v.u >> 16) & 1u)) >> 16;
    return (u16)r;
}
__device__ __forceinline__ uint32_t pkbf(float a, float b) {
    union { __hip_bfloat162 h; uint32_t w; } u;
    u.h = __float22bfloat162_rn(float2{a, b});
    return u.w;
}
__device__ __forceinline__ void store_out(u16* p, float v) { *p = f2bf(v); }
__device__ __forceinline__ void store_out(float* p, float v) { *p = v; }

__device__ __forceinline__ void async_ld16(const u16* g, u16* l) {
    __builtin_amdgcn_global_load_lds(
        (const __attribute__((address_space(1))) void*)g,
        (__attribute__((address_space(3))) void*)l, 16, 0, 0);
}

// ---------------------------------------------------------------------------
// x fp32 [4096*1024] -> bf16
// ---------------------------------------------------------------------------
__global__ void cvt_x(const float* __restrict__ x, u16* __restrict__ xb) {
    int i = (blockIdx.x * 256 + threadIdx.x) * 8;
    float4 a = *(const float4*)(x + i);
    float4 b = *(const float4*)(x + i + 4);
    union { uint32_t w[4]; uint4 v; } o;
    o.w[0] = pkbf(a.x, a.y); o.w[1] = pkbf(a.z, a.w);
    o.w[2] = pkbf(b.x, b.y); o.w[3] = pkbf(b.z, b.w);
    *(uint4*)(xb + i) = o.v;
}

// ---------------------------------------------------------------------------
// fp32 [1024][1024] -> bf16 transposed; z selects among 3 sources
// ---------------------------------------------------------------------------
__global__ void transpose3(const float* __restrict__ w0, const float* __restrict__ w1,
                           const float* __restrict__ w2, u16* __restrict__ out) {
    const int z = blockIdx.z;
    const float* in = (z == 0) ? w0 : (z == 1) ? w1 : w2;
    u16* o = out + (size_t)z * 1024 * 1024;
    __shared__ u16 tile[32][33];
    int x = blockIdx.x * 32 + threadIdx.x;
    int y0 = blockIdx.y * 32;
#pragma unroll
    for (int j = threadIdx.y; j < 32; j += 8)
        tile[j][threadIdx.x] = f2bf(in[(size_t)(y0 + j) * 1024 + x]);
    __syncthreads();
    int ox = blockIdx.y * 32 + threadIdx.x;
    int oy0 = blockIdx.x * 32;
#pragma unroll
    for (int j = threadIdx.y; j < 32; j += 8)
        o[(size_t)(oy0 + j) * 1024 + ox] = tile[threadIdx.x][j];
}

// ---------------------------------------------------------------------------
// GEMM (B^T bf16, async-LDS staging, BK=64, XOR-swizzled no-pad LDS):
// C = A[M,K] @ BT[N,K]^T + bias_f32. 128x128 tile, 32 MFMA per barrier pair.
// LDS row r stores cols (c ^ ((r&1)*32)) -- keeps global_load_lds lane
// contiguity AND full 32-bank coverage on b128 frag reads.
// ---------------------------------------------------------------------------
#define GBM 128
#define GBN 128
#define GBK 64

template <typename OutT>
__global__ __launch_bounds__(256) void gemm_bt(
    const u16* __restrict__ A, int lda,
    const u16* __restrict__ BT, int ldb,
    const float* __restrict__ bias0, const float* __restrict__ bias1,
    const float* __restrict__ bias2,
    OutT* __restrict__ C, int ldc, int K) {
    __shared__ __align__(16) u16 As[GBM * GBK];
    __shared__ __align__(16) u16 Bs[GBN * GBK];

    const int tid = threadIdx.x;
    const int wave = tid >> 6, lane = tid & 63;
    const int quad = lane >> 4, l16 = lane & 15;
    const int wr = wave >> 1, wc = wave & 1;
    const int m0 = blockIdx.y * GBM, n0 = blockIdx.x * GBN;

    const int seg = n0 >> 10;
    const float* bsel = (seg == 0) ? bias0 : (seg == 1) ? bias1 : bias2;

    f32x4 acc[4][4] = {};

    // staging: async i covers chunk c=i*4+wave (rows [c*8, c*8+8)); lane:
    // row = c*8 + (lane>>3), global col = ((lane&7)*8) ^ ((row&1)*32)
    const int lrow = lane >> 3;                       // 0..7
    const int lcol = ((lane & 7) * 8) ^ ((lrow & 1) * 32);
    const u16* Ag[4]; const u16* Bg[4];
    u16* AsB[4]; u16* BsB[4];
#pragma unroll
    for (int i = 0; i < 4; i++) {
        int c = i * 4 + wave;
        int row = c * 8 + lrow;
        Ag[i] = A + (size_t)(m0 + row) * lda + lcol;
        Bg[i] = BT + (size_t)(n0 + row) * ldb + lcol;
        AsB[i] = As + c * 512;
        BsB[i] = Bs + c * 512;
    }

    for (int kb = 0; kb < K; kb += GBK) {
#pragma unroll
        for (int i = 0; i < 4; i++) {
            async_ld16(Ag[i] + kb, AsB[i]);
            async_ld16(Bg[i] + kb, BsB[i]);
        }
        __syncthreads();

#pragma unroll
        for (int k2 = 0; k2 < 2; k2++) {
            const int col = (k2 * 32 + quad * 8) ^ ((l16 & 1) * 32);
            short8 af[4], bf[4];
#pragma unroll
            for (int mt = 0; mt < 4; mt++)
                af[mt] = *(const short8*)(As + (wr * 64 + mt * 16 + l16) * GBK + col);
#pragma unroll
            for (int nt = 0; nt < 4; nt++)
                bf[nt] = *(const short8*)(Bs + (wc * 64 + nt * 16 + l16) * GBK + col);
#pragma unroll
            for (int mt = 0; mt < 4; mt++)
#pragma unroll
                for (int nt = 0; nt < 4; nt++)
                    acc[mt][nt] = __builtin_amdgcn_mfma_f32_16x16x32_bf16(
                        af[mt], bf[nt], acc[mt][nt], 0, 0, 0);
        }
        __syncthreads();
    }

#pragma unroll
    for (int nt = 0; nt < 4; nt++) {
        int col = n0 + wc * 64 + nt * 16 + l16;
        float bv = bsel[col & 1023];
#pragma unroll
        for (int mt = 0; mt < 4; mt++) {
            int row = m0 + wr * 64 + mt * 16 + quad * 4;
#pragma unroll
            for (int r = 0; r < 4; r++)
                store_out(&C[(size_t)(row + r) * ldc + col], acc[mt][nt][r] + bv);
        }
    }
}

// ---------------------------------------------------------------------------
// Flash attention (unchanged from round 9): transposed-MFMA, zero P movement.
//   S^T = K (cs*Q)^T  (16x16x32, A=K from LDS, B=Q regs)
//   O^T += V^T P^T    (16x16x16: P^T C-layout == K=16 B-operand layout)
// BKV=128, 2 barriers/iter, no online max. In-place output to Q region.
// ---------------------------------------------------------------------------
#define SEQ 2048
#define BQ 64
#define BKV 128
#define LDK 72     // Ks row: 64 d + 8 pad
#define LDKV 136   // Vs row: 128 kk + 8 pad

__global__ __launch_bounds__(256) void attn(u16* __restrict__ QKV) {
    __shared__ __align__(16) u16 Ks[BKV * LDK];        // [kk][d]
    __shared__ __align__(16) u16 Vs[64 * LDKV];        // [d][kk] (transposed)

    const int tid = threadIdx.x;
    const int wave = tid >> 6, lane = tid & 63;
    const int quad = lane >> 4, l16 = lane & 15;
    const int h = blockIdx.y, bb = blockIdx.z;
    const int q0 = blockIdx.x * BQ;
    const size_t tok0 = (size_t)bb * SEQ;

    const u16* Qb = QKV + tok0 * 3072 + h * 64;
    const u16* Kb = QKV + tok0 * 3072 + 1024 + h * 64;
    const u16* Vb = QKV + tok0 * 3072 + 2048 + h * 64;

    const float cs = 0.18033688011112042f;  // (1/8) * log2(e)

    const int qrow = q0 + wave * 16 + l16;
    short8 aq[2];
    {
        union { short8 s; u16 u[8]; uint32_t w[4]; } qa, qb;
        qa.s = *(const short8*)(Qb + (size_t)qrow * 3072 + quad * 8);
        qb.s = *(const short8*)(Qb + (size_t)qrow * 3072 + 32 + quad * 8);
#pragma unroll
        for (int j = 0; j < 4; j++) {
            qa.w[j] = pkbf(bf2f(qa.u[2 * j]) * cs, bf2f(qa.u[2 * j + 1]) * cs);
            qb.w[j] = pkbf(bf2f(qb.u[2 * j]) * cs, bf2f(qb.u[2 * j + 1]) * cs);
        }
        aq[0] = qa.s; aq[1] = qb.s;
    }

    float l_i = 0.0f;
    f32x4 o[4] = {};

    const int srow = tid >> 2;           // 0..63
    const int scc = (tid & 3) * 16;      // 0/16/32/48
    const int pr = tid & 63;
    const int dg = wave;

    const u16* kg = Kb + (size_t)srow * 3072 + scc;
    const u16* vg = Vb + (size_t)(2 * pr) * 3072 + dg * 16;

    uint4 k0r = *(const uint4*)(kg);
    uint4 k1r = *(const uint4*)(kg + 8);
    uint4 k2r = *(const uint4*)(kg + (size_t)64 * 3072);
    uint4 k3r = *(const uint4*)(kg + (size_t)64 * 3072 + 8);
    uint4 va0 = *(const uint4*)(vg);
    uint4 va1 = *(const uint4*)(vg + 8);
    uint4 vb0 = *(const uint4*)(vg + 3072);
    uint4 vb1 = *(const uint4*)(vg + 3072 + 8);

    for (int j0 = 0; j0 < SEQ; j0 += BKV) {
        *(uint4*)(Ks + srow * LDK + scc) = k0r;
        *(uint4*)(Ks + srow * LDK + scc + 8) = k1r;
        *(uint4*)(Ks + (srow + 64) * LDK + scc) = k2r;
        *(uint4*)(Ks + (srow + 64) * LDK + scc + 8) = k3r;
        {
            union { uint4 v[2]; u16 u[16]; } a, b;
            a.v[0] = va0; a.v[1] = va1; b.v[0] = vb0; b.v[1] = vb1;
#pragma unroll
            for (int j = 0; j < 16; j++) {
                uint32_t w = (uint32_t)a.u[j] | ((uint32_t)b.u[j] << 16);
                *(uint32_t*)(Vs + (dg * 16 + j) * LDKV + 2 * pr) = w;
            }
        }
        __syncthreads();   // B1: staged tile visible

        if (j0 + BKV < SEQ) {
            size_t off = (size_t)(j0 + BKV) * 3072;
            k0r = *(const uint4*)(kg + off);
            k1r = *(const uint4*)(kg + off + 8);
            k2r = *(const uint4*)(kg + off + (size_t)64 * 3072);
            k3r = *(const uint4*)(kg + off + (size_t)64 * 3072 + 8);
            va0 = *(const uint4*)(vg + off);
            va1 = *(const uint4*)(vg + off + 8);
            vb0 = *(const uint4*)(vg + off + 3072);
            vb1 = *(const uint4*)(vg + off + 3072 + 8);
        }

        f32x4 st[8];
#pragma unroll
        for (int kkt = 0; kkt < 8; kkt++) {
            f32x4 s = {};
#pragma unroll
            for (int k2 = 0; k2 < 2; k2++) {
                short8 ak = *(const short8*)(Ks + (kkt * 16 + l16) * LDK + k2 * 32 + quad * 8);
                s = __builtin_amdgcn_mfma_f32_16x16x32_bf16(ak, aq[k2], s, 0, 0, 0);
            }
            st[kkt] = s;
        }

#pragma unroll
        for (int kkt = 0; kkt < 8; kkt++)
#pragma unroll
            for (int r = 0; r < 4; r++)
                st[kkt][r] = __builtin_amdgcn_exp2f(st[kkt][r]);

        {
            float ls = 0.0f;
#pragma unroll
            for (int kkt = 0; kkt < 8; kkt++)
#pragma unroll
                for (int r = 0; r < 4; r++) ls += st[kkt][r];
            ls += __shfl_xor(ls, 16, 64);
            ls += __shfl_xor(ls, 32, 64);
            l_i += ls;
        }

#pragma unroll
        for (int kkt = 0; kkt < 8; kkt++) {
            union { uint32_t w[2]; s4v s; } bp;
            bp.w[0] = pkbf(st[kkt][0], st[kkt][1]);
            bp.w[1] = pkbf(st[kkt][2], st[kkt][3]);
#pragma unroll
            for (int dt = 0; dt < 4; dt++) {
                s4v av = *(const s4v*)(Vs + (dt * 16 + l16) * LDKV + kkt * 16 + quad * 4);
                o[dt] = __builtin_amdgcn_mfma_f32_16x16x16bf16_1k(av, bp.s, o[dt], 0, 0, 0);
            }
        }

        __syncthreads();   // B2: Ks/Vs reads done before next staging
    }

    const float inv_l = 1.0f / l_i;
    u16* orow = QKV + (tok0 + qrow) * 3072 + h * 64;
#pragma unroll
    for (int dt = 0; dt < 4; dt++) {
        uint32_t w0 = pkbf(o[dt][0] * inv_l, o[dt][1] * inv_l);
        uint32_t w1 = pkbf(o[dt][2] * inv_l, o[dt][3] * inv_l);
        uint2 w = {w0, w1};
        *(uint2*)(orow + dt * 16 + quad * 4) = w;
    }
}

// ---------------------------------------------------------------------------
extern "C" void kernel_launch(void* const* d_in, const int* in_sizes, int n_in,
                              void* d_out, int out_size, void* d_ws, size_t ws_size,
                              hipStream_t stream) {
    const float* x  = (const float*)d_in[0];
    const float* wq = (const float*)d_in[1];
    const float* bq = (const float*)d_in[2];
    const float* wk = (const float*)d_in[3];
    const float* bk = (const float*)d_in[4];
    const float* wv = (const float*)d_in[5];
    const float* bv = (const float*)d_in[6];
    const float* wo = (const float*)d_in[7];
    const float* bo = (const float*)d_in[8];
    (void)in_sizes; (void)n_in; (void)out_size; (void)ws_size;

    u16* QKV = (u16*)d_ws;                              // [4096][3072] bf16, 24 MB
    u16* wT  = QKV + (size_t)4096 * 3072;               // [3][1024][1024] bf16, 6 MB
    u16* xb  = wT + (size_t)3 * 1024 * 1024;            // [4096][1024] bf16, 8 MB
    u16* woT = xb;                                      // reuses xb after gemm1

    cvt_x<<<dim3(2048), dim3(256), 0, stream>>>(x, xb);
    transpose3<<<dim3(32, 32, 3), dim3(32, 8), 0, stream>>>(wq, wk, wv, wT);
    gemm_bt<u16><<<dim3(24, 32), 256, 0, stream>>>(xb, 1024, wT, 1024, bq, bk, bv,
                                                   QKV, 3072, 1024);
    transpose3<<<dim3(32, 32, 1), dim3(32, 8), 0, stream>>>(wo, wo, wo, woT);
    attn<<<dim3(32, 16, 2), 256, 0, stream>>>(QKV);
    gemm_bt<float><<<dim3(8, 32), 256, 0, stream>>>(QKV, 3072, woT, 1024, bo, bo, bo,
                                                    (float*)d_out, 1024, 1024);
}

// Round 11
// 214.542 us; speedup vs baseline: 1.1337x; 1.1337x over previous
//
#include <hip/hip_runtime.h>
#include <hip/hip_bf16.h>
#include <stdint.h>

typedef unsigned short u16;
typedef __attribute__((ext_vector_type(8))) short short8;
typedef __attribute__((ext_vector_type(4))) short s4v;
typedef __attribute__((ext_vector_type(4))) float f32x4;

__device__ __forceinline__ float bf2f(u16 u) {
    union { uint32_t u; float f; } v; v.u = ((uint32_t)u) << 16; return v.f;
}
__device__ __forceinline__ u16 f2bf(float f) {
    union { float f; uint32_t u; } v; v.f = f;
    uint32_t r = (v.u + 0x7fffu + ((v.u >> 16) & 1u)) >> 16;
    return (u16)r;
}
__device__ __forceinline__ uint32_t pkbf(float a, float b) {
    union { __hip_bfloat162 h; uint32_t w; } u;
    u.h = __float22bfloat162_rn(float2{a, b});
    return u.w;
}
__device__ __forceinline__ void store_out(u16* p, float v) { *p = f2bf(v); }
__device__ __forceinline__ void store_out(float* p, float v) { *p = v; }

__device__ __forceinline__ void async_ld16(const u16* g, u16* l) {
    __builtin_amdgcn_global_load_lds(
        (const __attribute__((address_space(1))) void*)g,
        (__attribute__((address_space(3))) void*)l, 16, 0, 0);
}

// ---------------------------------------------------------------------------
// x fp32 [4096*1024] -> bf16
// ---------------------------------------------------------------------------
__global__ void cvt_x(const float* __restrict__ x, u16* __restrict__ xb) {
    int i = (blockIdx.x * 256 + threadIdx.x) * 8;
    float4 a = *(const float4*)(x + i);
    float4 b = *(const float4*)(x + i + 4);
    union { uint32_t w[4]; uint4 v; } o;
    o.w[0] = pkbf(a.x, a.y); o.w[1] = pkbf(a.z, a.w);
    o.w[2] = pkbf(b.x, b.y); o.w[3] = pkbf(b.z, b.w);
    *(uint4*)(xb + i) = o.v;
}

// ---------------------------------------------------------------------------
// fp32 [1024][1024] -> bf16 transposed; z selects among 3 sources
// ---------------------------------------------------------------------------
__global__ void transpose3(const float* __restrict__ w0, const float* __restrict__ w1,
                           const float* __restrict__ w2, u16* __restrict__ out) {
    const int z = blockIdx.z;
    const float* in = (z == 0) ? w0 : (z == 1) ? w1 : w2;
    u16* o = out + (size_t)z * 1024 * 1024;
    __shared__ u16 tile[32][33];
    int x = blockIdx.x * 32 + threadIdx.x;
    int y0 = blockIdx.y * 32;
#pragma unroll
    for (int j = threadIdx.y; j < 32; j += 8)
        tile[j][threadIdx.x] = f2bf(in[(size_t)(y0 + j) * 1024 + x]);
    __syncthreads();
    int ox = blockIdx.y * 32 + threadIdx.x;
    int oy0 = blockIdx.x * 32;
#pragma unroll
    for (int j = threadIdx.y; j < 32; j += 8)
        o[(size_t)(oy0 + j) * 1024 + ox] = tile[threadIdx.x][j];
}

// ---------------------------------------------------------------------------
// GEMM (round-9 version: B^T bf16, async-LDS staging, BK=32, no-pad [128][32]).
// ---------------------------------------------------------------------------
#define GBM 128
#define GBN 128
#define GBK 32

template <typename OutT>
__global__ __launch_bounds__(256) void gemm_bt(
    const u16* __restrict__ A, int lda,
    const u16* __restrict__ BT, int ldb,
    const float* __restrict__ bias0, const float* __restrict__ bias1,
    const float* __restrict__ bias2,
    OutT* __restrict__ C, int ldc, int K) {
    __shared__ __align__(16) u16 As[GBM * GBK];
    __shared__ __align__(16) u16 Bs[GBN * GBK];

    const int tid = threadIdx.x;
    const int wave = tid >> 6, lane = tid & 63;
    const int quad = lane >> 4, l16 = lane & 15;
    const int wr = wave >> 1, wc = wave & 1;
    const int m0 = blockIdx.y * GBM, n0 = blockIdx.x * GBN;

    const int seg = n0 >> 10;
    const float* bsel = (seg == 0) ? bias0 : (seg == 1) ? bias1 : bias2;

    f32x4 acc[4][4] = {};

    const int srow = tid >> 2;
    const int scol = (tid & 3) * 8;
    const u16* Ag0 = A + (size_t)(m0 + srow) * lda + scol;
    const u16* Ag1 = Ag0 + (size_t)64 * lda;
    const u16* Bg0 = BT + (size_t)(n0 + srow) * ldb + scol;
    const u16* Bg1 = Bg0 + (size_t)64 * ldb;
    u16* As0 = As + (wave << 9);
    u16* As1 = As0 + 64 * GBK;
    u16* Bs0 = Bs + (wave << 9);
    u16* Bs1 = Bs0 + 64 * GBK;

    for (int kb = 0; kb < K; kb += GBK) {
        async_ld16(Ag0 + kb, As0);
        async_ld16(Ag1 + kb, As1);
        async_ld16(Bg0 + kb, Bs0);
        async_ld16(Bg1 + kb, Bs1);
        __syncthreads();

        short8 af[4], bf[4];
#pragma unroll
        for (int mt = 0; mt < 4; mt++)
            af[mt] = *(const short8*)(As + (wr * 64 + mt * 16 + l16) * GBK + quad * 8);
#pragma unroll
        for (int nt = 0; nt < 4; nt++)
            bf[nt] = *(const short8*)(Bs + (wc * 64 + nt * 16 + l16) * GBK + quad * 8);
#pragma unroll
        for (int mt = 0; mt < 4; mt++)
#pragma unroll
            for (int nt = 0; nt < 4; nt++)
                acc[mt][nt] = __builtin_amdgcn_mfma_f32_16x16x32_bf16(
                    af[mt], bf[nt], acc[mt][nt], 0, 0, 0);
        __syncthreads();
    }

#pragma unroll
    for (int nt = 0; nt < 4; nt++) {
        int col = n0 + wc * 64 + nt * 16 + l16;
        float bv = bsel[col & 1023];
#pragma unroll
        for (int mt = 0; mt < 4; mt++) {
            int row = m0 + wr * 64 + mt * 16 + quad * 4;
#pragma unroll
            for (int r = 0; r < 4; r++)
                store_out(&C[(size_t)(row + r) * ldc + col], acc[mt][nt][r] + bv);
        }
    }
}

// ---------------------------------------------------------------------------
// Flash attention, BQ=128 (2 q-slabs/wave): staged K/V tile + A-operand frags
// amortize over 2x MFMAs. Transposed-MFMA, zero P movement, BKV=128,
// 2 barriers/iter, no online max. In-place output to Q region.
// ---------------------------------------------------------------------------
#define SEQ 2048
#define BQT 128
#define BKV 128
#define LDK 72     // Ks row: 64 d + 8 pad
#define LDKV 136   // Vs row: 128 kk + 8 pad

__global__ __launch_bounds__(256) void attn(u16* __restrict__ QKV) {
    __shared__ __align__(16) u16 Ks[BKV * LDK];        // [kk][d]
    __shared__ __align__(16) u16 Vs[64 * LDKV];        // [d][kk] (transposed)

    const int tid = threadIdx.x;
    const int wave = tid >> 6, lane = tid & 63;
    const int quad = lane >> 4, l16 = lane & 15;
    const int h = blockIdx.y, bb = blockIdx.z;
    const int q0 = blockIdx.x * BQT;
    const size_t tok0 = (size_t)bb * SEQ;

    const u16* Qb = QKV + tok0 * 3072 + h * 64;
    const u16* Kb = QKV + tok0 * 3072 + 1024 + h * 64;
    const u16* Vb = QKV + tok0 * 3072 + 2048 + h * 64;

    const float cs = 0.18033688011112042f;  // (1/8) * log2(e)

    // Q as MFMA B-operand for two q-slabs (s=0,1): q = q0 + s*64 + wave*16 + l16
    int qr[2];
    qr[0] = q0 + wave * 16 + l16;
    qr[1] = qr[0] + 64;
    short8 aq[2][2];
#pragma unroll
    for (int s = 0; s < 2; s++) {
        union { short8 v; u16 u[8]; uint32_t w[4]; } qa, qb;
        qa.v = *(const short8*)(Qb + (size_t)qr[s] * 3072 + quad * 8);
        qb.v = *(const short8*)(Qb + (size_t)qr[s] * 3072 + 32 + quad * 8);
#pragma unroll
        for (int j = 0; j < 4; j++) {
            qa.w[j] = pkbf(bf2f(qa.u[2 * j]) * cs, bf2f(qa.u[2 * j + 1]) * cs);
            qb.w[j] = pkbf(bf2f(qb.u[2 * j]) * cs, bf2f(qb.u[2 * j + 1]) * cs);
        }
        aq[s][0] = qa.v; aq[s][1] = qb.v;
    }

    float l_i[2] = {0.0f, 0.0f};
    f32x4 o[2][4] = {};

    const int srow = tid >> 2;           // 0..63
    const int scc = (tid & 3) * 16;      // 0/16/32/48
    const int pr = tid & 63;
    const int dg = wave;

    const u16* kg = Kb + (size_t)srow * 3072 + scc;
    const u16* vg = Vb + (size_t)(2 * pr) * 3072 + dg * 16;

    uint4 k0r = *(const uint4*)(kg);
    uint4 k1r = *(const uint4*)(kg + 8);
    uint4 k2r = *(const uint4*)(kg + (size_t)64 * 3072);
    uint4 k3r = *(const uint4*)(kg + (size_t)64 * 3072 + 8);
    uint4 va0 = *(const uint4*)(vg);
    uint4 va1 = *(const uint4*)(vg + 8);
    uint4 vb0 = *(const uint4*)(vg + 3072);
    uint4 vb1 = *(const uint4*)(vg + 3072 + 8);

    for (int j0 = 0; j0 < SEQ; j0 += BKV) {
        // ---- stage K rows + pair-packed V^T ----
        *(uint4*)(Ks + srow * LDK + scc) = k0r;
        *(uint4*)(Ks + srow * LDK + scc + 8) = k1r;
        *(uint4*)(Ks + (srow + 64) * LDK + scc) = k2r;
        *(uint4*)(Ks + (srow + 64) * LDK + scc + 8) = k3r;
        {
            union { uint4 v[2]; u16 u[16]; } a, b;
            a.v[0] = va0; a.v[1] = va1; b.v[0] = vb0; b.v[1] = vb1;
#pragma unroll
            for (int j = 0; j < 16; j++) {
                uint32_t w = (uint32_t)a.u[j] | ((uint32_t)b.u[j] << 16);
                *(uint32_t*)(Vs + (dg * 16 + j) * LDKV + 2 * pr) = w;
            }
        }
        __syncthreads();   // B1: staged tile visible

        // ---- prefetch next tile ----
        if (j0 + BKV < SEQ) {
            size_t off = (size_t)(j0 + BKV) * 3072;
            k0r = *(const uint4*)(kg + off);
            k1r = *(const uint4*)(kg + off + 8);
            k2r = *(const uint4*)(kg + off + (size_t)64 * 3072);
            k3r = *(const uint4*)(kg + off + (size_t)64 * 3072 + 8);
            va0 = *(const uint4*)(vg + off);
            va1 = *(const uint4*)(vg + off + 8);
            vb0 = *(const uint4*)(vg + off + 3072);
            vb1 = *(const uint4*)(vg + off + 3072 + 8);
        }

        // ---- S^T = K (cs*Q)^T for both q-slabs (shared ak frags) ----
        f32x4 st[2][8];
#pragma unroll
        for (int kkt = 0; kkt < 8; kkt++) {
            f32x4 s0 = {}, s1 = {};
#pragma unroll
            for (int k2 = 0; k2 < 2; k2++) {
                short8 ak = *(const short8*)(Ks + (kkt * 16 + l16) * LDK + k2 * 32 + quad * 8);
                s0 = __builtin_amdgcn_mfma_f32_16x16x32_bf16(ak, aq[0][k2], s0, 0, 0, 0);
                s1 = __builtin_amdgcn_mfma_f32_16x16x32_bf16(ak, aq[1][k2], s1, 0, 0, 0);
            }
            st[0][kkt] = s0; st[1][kkt] = s1;
        }

        // ---- P^T = exp2(S^T); denoms ----
#pragma unroll
        for (int s = 0; s < 2; s++) {
            float ls = 0.0f;
#pragma unroll
            for (int kkt = 0; kkt < 8; kkt++)
#pragma unroll
                for (int r = 0; r < 4; r++) {
                    st[s][kkt][r] = __builtin_amdgcn_exp2f(st[s][kkt][r]);
                    ls += st[s][kkt][r];
                }
            ls += __shfl_xor(ls, 16, 64);
            ls += __shfl_xor(ls, 32, 64);
            l_i[s] += ls;
        }

        // ---- O^T += V^T P^T (shared av frags) ----
#pragma unroll
        for (int kkt = 0; kkt < 8; kkt++) {
            union { uint32_t w[2]; s4v s; } bp0, bp1;
            bp0.w[0] = pkbf(st[0][kkt][0], st[0][kkt][1]);
            bp0.w[1] = pkbf(st[0][kkt][2], st[0][kkt][3]);
            bp1.w[0] = pkbf(st[1][kkt][0], st[1][kkt][1]);
            bp1.w[1] = pkbf(st[1][kkt][2], st[1][kkt][3]);
#pragma unroll
            for (int dt = 0; dt < 4; dt++) {
                s4v av = *(const s4v*)(Vs + (dt * 16 + l16) * LDKV + kkt * 16 + quad * 4);
                o[0][dt] = __builtin_amdgcn_mfma_f32_16x16x16bf16_1k(av, bp0.s, o[0][dt], 0, 0, 0);
                o[1][dt] = __builtin_amdgcn_mfma_f32_16x16x16bf16_1k(av, bp1.s, o[1][dt], 0, 0, 0);
            }
        }

        __syncthreads();   // B2: Ks/Vs reads done before next staging
    }

    // ---- finalize both slabs ----
#pragma unroll
    for (int s = 0; s < 2; s++) {
        const float inv_l = 1.0f / l_i[s];
        u16* orow = QKV + (tok0 + qr[s]) * 3072 + h * 64;
#pragma unroll
        for (int dt = 0; dt < 4; dt++) {
            uint32_t w0 = pkbf(o[s][dt][0] * inv_l, o[s][dt][1] * inv_l);
            uint32_t w1 = pkbf(o[s][dt][2] * inv_l, o[s][dt][3] * inv_l);
            uint2 w = {w0, w1};
            *(uint2*)(orow + dt * 16 + quad * 4) = w;
        }
    }
}

// ---------------------------------------------------------------------------
extern "C" void kernel_launch(void* const* d_in, const int* in_sizes, int n_in,
                              void* d_out, int out_size, void* d_ws, size_t ws_size,
                              hipStream_t stream) {
    const float* x  = (const float*)d_in[0];
    const float* wq = (const float*)d_in[1];
    const float* bq = (const float*)d_in[2];
    const float* wk = (const float*)d_in[3];
    const float* bk = (const float*)d_in[4];
    const float* wv = (const float*)d_in[5];
    const float* bv = (const float*)d_in[6];
    const float* wo = (const float*)d_in[7];
    const float* bo = (const float*)d_in[8];
    (void)in_sizes; (void)n_in; (void)out_size; (void)ws_size;

    u16* QKV = (u16*)d_ws;                              // [4096][3072] bf16, 24 MB
    u16* wT  = QKV + (size_t)4096 * 3072;               // [3][1024][1024] bf16, 6 MB
    u16* xb  = wT + (size_t)3 * 1024 * 1024;            // [4096][1024] bf16, 8 MB
    u16* woT = xb;                                      // reuses xb after gemm1

    cvt_x<<<dim3(2048), dim3(256), 0, stream>>>(x, xb);
    transpose3<<<dim3(32, 32, 3), dim3(32, 8), 0, stream>>>(wq, wk, wv, wT);
    gemm_bt<u16><<<dim3(24, 32), 256, 0, stream>>>(xb, 1024, wT, 1024, bq, bk, bv,
                                                   QKV, 3072, 1024);
    transpose3<<<dim3(32, 32, 1), dim3(32, 8), 0, stream>>>(wo, wo, wo, woT);
    attn<<<dim3(16, 16, 2), 256, 0, stream>>>(QKV);
    gemm_bt<float><<<dim3(8, 32), 256, 0, stream>>>(QKV, 3072, woT, 1024, bo, bo, bo,
                                                    (float*)d_out, 1024, 1024);
}